// Round 1
// baseline (833.236 us; speedup 1.0000x reference)
//
#include <hip/hip_runtime.h>
#include <math.h>

#define M_ROWS 32768
#define N_CLS  2048
#define NGRP   8
#define CPG    256
#define NS     10
#define EDIM   400
#define KC     16
#define BM     32

// workspace layout (float offsets)
#define WS_EE   0
#define WS_XX   (WS_EE + N_CLS)
#define WS_GSUM (WS_XX + M_ROWS)
#define WS_RMSE (WS_GSUM + M_ROWS * NGRP)
#define WS_HIST (WS_RMSE + M_ROWS)

// ---------------- row sum-of-squares: one wave per row ----------------
__global__ __launch_bounds__(256) void k_sumsq(const float* __restrict__ in,
                                               float* __restrict__ out, int rows) {
    int wave = (blockIdx.x * blockDim.x + threadIdx.x) >> 6;
    int lane = threadIdx.x & 63;
    if (wave >= rows) return;
    const float* r = in + (size_t)wave * EDIM;
    float s = 0.f;
    for (int d = lane; d < EDIM; d += 64) { float v = r[d]; s = fmaf(v, v, s); }
    #pragma unroll
    for (int o = 32; o; o >>= 1) s += __shfl_xor(s, o, 64);
    if (lane == 0) out[wave] = s;
}

// ---------------- distance GEMM: block = 32 rows x 256 cols (one full group) ----------------
__global__ __launch_bounds__(256) void k_dist(const float* __restrict__ x,
                                              const float* __restrict__ emb,
                                              const float* __restrict__ xx,
                                              const float* __restrict__ ee,
                                              float* __restrict__ enc,
                                              float* __restrict__ gsum) {
    __shared__ float As[KC][36];    // padded: +4 keeps float4 alignment, kills write conflicts
    __shared__ float Bs[KC][260];

    const int tid = threadIdx.x;
    const int m0  = blockIdx.x * BM;
    const int g   = blockIdx.y;
    const int j0  = g * CPG;
    const int ty  = tid >> 5;       // 0..7 -> 4 rows each
    const int tx  = tid & 31;       // 0..31 -> cols tx*4 and 128+tx*4

    float acc[4][8];
    #pragma unroll
    for (int i = 0; i < 4; ++i)
        #pragma unroll
        for (int j = 0; j < 8; ++j) acc[i][j] = 0.f;

    const int kk    = tid & 15;
    const int rbase = tid >> 4;     // 0..15

    for (int k0 = 0; k0 < EDIM; k0 += KC) {
        // stage A: 32 rows x 16 k
        #pragma unroll
        for (int p = 0; p < 2; ++p) {
            int r = p * 16 + rbase;
            As[kk][r] = x[(size_t)(m0 + r) * EDIM + k0 + kk];
        }
        // stage B: 256 cols x 16 k
        #pragma unroll
        for (int p = 0; p < 16; ++p) {
            int c = p * 16 + rbase;
            Bs[kk][c] = emb[(size_t)(j0 + c) * EDIM + k0 + kk];
        }
        __syncthreads();
        #pragma unroll
        for (int k = 0; k < KC; ++k) {
            float4 a  = *(const float4*)&As[k][ty * 4];
            float4 b0 = *(const float4*)&Bs[k][tx * 4];
            float4 b1 = *(const float4*)&Bs[k][128 + tx * 4];
            float av[4] = {a.x, a.y, a.z, a.w};
            float bv[8] = {b0.x, b0.y, b0.z, b0.w, b1.x, b1.y, b1.z, b1.w};
            #pragma unroll
            for (int i = 0; i < 4; ++i)
                #pragma unroll
                for (int j = 0; j < 8; ++j)
                    acc[i][j] = fmaf(av[i], bv[j], acc[i][j]);
        }
        __syncthreads();
    }

    // epilogue: d = xx + ee - 2*dot ; write 1/d ; accumulate group row-sums
    float rp[4];
    #pragma unroll
    for (int i = 0; i < 4; ++i) {
        int m = m0 + ty * 4 + i;
        float xm = xx[m];
        float rsum = 0.f;
        float* erow = enc + (size_t)m * N_CLS + j0;
        #pragma unroll
        for (int j = 0; j < 8; ++j) {
            int c = (j < 4) ? (tx * 4 + j) : (128 + tx * 4 + (j - 4));
            float t = xm + ee[j0 + c];
            float d = fmaf(-2.f, acc[i][j], t);
            rsum += d;
            erow[c] = 1.0f / d;
        }
        rp[i] = rsum;
    }
    #pragma unroll
    for (int i = 0; i < 4; ++i) {
        float s = rp[i];
        s += __shfl_xor(s, 1, 64);
        s += __shfl_xor(s, 2, 64);
        s += __shfl_xor(s, 4, 64);
        s += __shfl_xor(s, 8, 64);
        s += __shfl_xor(s, 16, 64);
        if (tx == 0) gsum[(size_t)(m0 + ty * 4 + i) * NGRP + g] = s;
    }
}

// ---------------- per-row selection, top-10, gather-sum: one wave per row ----------------
__global__ __launch_bounds__(256) void k_select(const float* __restrict__ x,
                                                const float* __restrict__ emb,
                                                const float* __restrict__ enc,
                                                const float* __restrict__ gsum,
                                                float* __restrict__ out0,
                                                float* __restrict__ rmse,
                                                unsigned int* __restrict__ hist) {
    const int wave = threadIdx.x >> 6;
    const int lane = threadIdx.x & 63;
    const int m = blockIdx.x * 4 + wave;

    // group argmin (sum comparison == mean comparison; first index wins ties)
    const float* gs = gsum + (size_t)m * NGRP;
    float bestv = gs[0]; int bestg = 0;
    #pragma unroll
    for (int g = 1; g < NGRP; ++g) { float v = gs[g]; if (v < bestv) { bestv = v; bestg = g; } }
    const int j0 = bestg * CPG;

    // load the stored probs (1/d) for the chosen group: identical bits to encodings
    const float* pr = enc + (size_t)m * N_CLS + j0;
    float v[4];
    #pragma unroll
    for (int s = 0; s < 4; ++s) v[s] = pr[lane + 64 * s];

    // iterative top-10: max value, ties -> lowest index (matches lax.top_k)
    float pv[NS]; int pidx[NS];
    #pragma unroll
    for (int t = 0; t < NS; ++t) {
        float bv = v[0]; int bs = 0;
        #pragma unroll
        for (int s = 1; s < 4; ++s) if (v[s] > bv) { bv = v[s]; bs = s; }
        int bidx = lane + 64 * bs;
        #pragma unroll
        for (int o = 1; o < 64; o <<= 1) {
            float ov = __shfl_xor(bv, o, 64);
            int   oi = __shfl_xor(bidx, o, 64);
            if (ov > bv || (ov == bv && oi < bidx)) { bv = ov; bidx = oi; }
        }
        pv[t] = bv; pidx[t] = bidx;
        if ((bidx & 63) == lane) v[bidx >> 6] = -INFINITY;
    }

    // L1-normalized weights (p > 0)
    float psum = 0.f;
    #pragma unroll
    for (int t = 0; t < NS; ++t) psum += pv[t];
    float wnorm = fmaxf(psum, 1e-12f);
    float w[NS]; int gi[NS];
    #pragma unroll
    for (int t = 0; t < NS; ++t) { w[t] = pv[t] / wnorm; gi[t] = j0 + pidx[t]; }

    if (lane == 0) atomicAdd(&hist[gi[0]], 1u);

    // weighted gather-sum + straight-through + per-row mse partial
    const float* xr = x + (size_t)m * EDIM;
    float* orow = out0 + (size_t)m * EDIM;
    float sq = 0.f;
    for (int d = lane; d < EDIM; d += 64) {
        float o = 0.f;
        #pragma unroll
        for (int t = 0; t < NS; ++t) o = fmaf(w[t], emb[(size_t)gi[t] * EDIM + d], o);
        float xv = xr[d];
        float diff = xv - o;           // mse uses true output
        sq = fmaf(diff, diff, sq);
        orow[d] = (o - xv) + xv;       // match ref's straight-through rounding
    }
    #pragma unroll
    for (int o = 32; o; o >>= 1) sq += __shfl_xor(sq, o, 64);
    if (lane == 0) rmse[m] = sq;
}

// ---------------- final deterministic reduction: loss + entropy ----------------
__global__ __launch_bounds__(1024) void k_final(const float* __restrict__ rmse,
                                                const unsigned int* __restrict__ hist,
                                                float* __restrict__ loss_out,
                                                float* __restrict__ ent_out) {
    __shared__ float red[1024];
    const int t = threadIdx.x;

    float s = 0.f;
    for (int i = t; i < M_ROWS; i += 1024) s += rmse[i];
    red[t] = s; __syncthreads();
    for (int off = 512; off; off >>= 1) {
        if (t < off) red[t] += red[t + off];
        __syncthreads();
    }
    if (t == 0) {
        float q = red[0] / 13107200.0f;   // mean over M*EDIM
        loss_out[0] = q + 0.25f * q;      // q_latent + COMMITMENT * e_latent (equal values)
    }
    __syncthreads();

    float e = 0.f;
    for (int i = t; i < N_CLS; i += 1024) {
        unsigned int h = hist[i];
        if (h > 0) {
            float prb = (float)h / 32768.0f;
            e -= prb * logf(prb);
        }
    }
    red[t] = e; __syncthreads();
    for (int off = 512; off; off >>= 1) {
        if (t < off) red[t] += red[t + off];
        __syncthreads();
    }
    if (t == 0) ent_out[0] = red[0];
}

extern "C" void kernel_launch(void* const* d_in, const int* in_sizes, int n_in,
                              void* d_out, int out_size, void* d_ws, size_t ws_size,
                              hipStream_t stream) {
    const float* x   = (const float*)d_in[0];   // [32768, 400]
    const float* emb = (const float*)d_in[1];   // [2048, 400]

    float* out      = (float*)d_out;
    float* loss_out = out;                       // [1]
    float* out0     = out + 1;                   // [32768*400]
    float* ent_out  = out + 1 + M_ROWS * EDIM;   // [1]
    float* enc      = out + 2 + M_ROWS * EDIM;   // [32768*2048]

    float* ws   = (float*)d_ws;
    float* ee   = ws + WS_EE;
    float* xx   = ws + WS_XX;
    float* gsum = ws + WS_GSUM;
    float* rmse = ws + WS_RMSE;
    unsigned int* hist = (unsigned int*)(ws + WS_HIST);

    hipMemsetAsync(hist, 0, N_CLS * sizeof(unsigned int), stream);

    k_sumsq<<<N_CLS / 4, 256, 0, stream>>>(emb, ee, N_CLS);
    k_sumsq<<<M_ROWS / 4, 256, 0, stream>>>(x, xx, M_ROWS);

    dim3 g2(M_ROWS / BM, NGRP);
    k_dist<<<g2, 256, 0, stream>>>(x, emb, xx, ee, enc, gsum);

    k_select<<<M_ROWS / 4, 256, 0, stream>>>(x, emb, enc, gsum, out0, rmse, hist);

    k_final<<<1, 1024, 0, stream>>>(rmse, hist, loss_out, ent_out);
}

// Round 2
// 364.535 us; speedup vs baseline: 2.2858x; 2.2858x over previous
//
#include <hip/hip_runtime.h>
#include <math.h>

#define M_ROWS 32768
#define N_CLS  2048
#define NGRP   8
#define CPG    256
#define NS     10
#define EDIM   400
#define KPAD   416            // 13 * 32, zero-padded
#define NKT    13
#define BK     32

typedef _Float16 f16x8 __attribute__((ext_vector_type(8)));
typedef float f32x4 __attribute__((ext_vector_type(4)));

__device__ __forceinline__ void gld_lds16(const void* g, void* l) {
    __builtin_amdgcn_global_load_lds(
        (const __attribute__((address_space(1))) unsigned int*)g,
        (__attribute__((address_space(3))) unsigned int*)l, 16, 0, 0);
}

// ---------------- split fp32 -> f16 hi/lo (K padded to 416) + row sum-of-squares ----------------
__global__ __launch_bounds__(256) void k_split(const float* __restrict__ in,
                                               unsigned short* __restrict__ hi,
                                               unsigned short* __restrict__ lo,
                                               float* __restrict__ ss, int rows) {
    int row  = blockIdx.x * 4 + (threadIdx.x >> 6);
    int lane = threadIdx.x & 63;
    if (row >= rows) return;
    const float* src = in + (size_t)row * EDIM;
    unsigned short* ph = hi + (size_t)row * KPAD;
    unsigned short* pl = lo + (size_t)row * KPAD;
    float s = 0.f;
    #pragma unroll
    for (int q = 0; q < 2; ++q) {
        int c4 = lane + q * 64;
        if (c4 < KPAD / 4) {
            int k = c4 * 4;
            float4 v = make_float4(0.f, 0.f, 0.f, 0.f);
            if (k < EDIM) v = *(const float4*)(src + k);
            float va[4] = {v.x, v.y, v.z, v.w};
            ushort4 H, L;
            unsigned short ha[4], la[4];
            #pragma unroll
            for (int t = 0; t < 4; ++t) {
                float f = va[t];
                _Float16 h = (_Float16)f;
                _Float16 l2 = (_Float16)(f - (float)h);
                ha[t] = __builtin_bit_cast(unsigned short, h);
                la[t] = __builtin_bit_cast(unsigned short, l2);
                s = fmaf(f, f, s);
            }
            H.x = ha[0]; H.y = ha[1]; H.z = ha[2]; H.w = ha[3];
            L.x = la[0]; L.y = la[1]; L.z = la[2]; L.w = la[3];
            *(ushort4*)(ph + k) = H;
            *(ushort4*)(pl + k) = L;
        }
    }
    #pragma unroll
    for (int o = 32; o; o >>= 1) s += __shfl_xor(s, o, 64);
    if (lane == 0) ss[row] = s;
}

// ---------------- row sum-of-squares (fallback path only) ----------------
__global__ __launch_bounds__(256) void k_sumsq(const float* __restrict__ in,
                                               float* __restrict__ out, int rows) {
    int wave = (blockIdx.x * blockDim.x + threadIdx.x) >> 6;
    int lane = threadIdx.x & 63;
    if (wave >= rows) return;
    const float* r = in + (size_t)wave * EDIM;
    float s = 0.f;
    for (int d = lane; d < EDIM; d += 64) { float v = r[d]; s = fmaf(v, v, s); }
    #pragma unroll
    for (int o = 32; o; o >>= 1) s += __shfl_xor(s, o, 64);
    if (lane == 0) out[wave] = s;
}

// ---------------- f16-split MFMA distance GEMM: 128x128 tile, BK=32, 4 waves ----------------
__global__ __launch_bounds__(256, 3) void k_dist_mfma(
    const unsigned short* __restrict__ xhi, const unsigned short* __restrict__ xlo,
    const unsigned short* __restrict__ ehi, const unsigned short* __restrict__ elo,
    const float* __restrict__ xx, const float* __restrict__ ee,
    float* __restrict__ enc, float* __restrict__ gsumP) {
    __shared__ __attribute__((aligned(16))) _Float16 Ah[128][BK];
    __shared__ __attribute__((aligned(16))) _Float16 Al[128][BK];
    __shared__ __attribute__((aligned(16))) _Float16 Bh[128][BK];
    __shared__ __attribute__((aligned(16))) _Float16 Bl[128][BK];

    const int tid  = threadIdx.x;
    const int m0   = blockIdx.x * 128;
    const int n0   = blockIdx.y * 128;
    const int lane = tid & 63, wid = tid >> 6;
    const int wr = (wid >> 1) * 64, wc = (wid & 1) * 64;
    const int lr = lane & 15, ko = lane >> 4;

    f32x4 acc[4][4];
    #pragma unroll
    for (int i = 0; i < 4; ++i)
        #pragma unroll
        for (int j = 0; j < 4; ++j) { f32x4 z = {0.f, 0.f, 0.f, 0.f}; acc[i][j] = z; }

    for (int kt = 0; kt < NKT; ++kt) {
        const int k0 = kt * BK;
        // stage: 4 arrays x 512 chunks of 16B, linear LDS, per-lane global addr
        #pragma unroll
        for (int q = 0; q < 2; ++q) {
            int c = q * 256 + tid;
            int row = c >> 2, kc = c & 3;
            size_t goA = (size_t)(m0 + row) * KPAD + k0 + kc * 8;
            size_t goB = (size_t)(n0 + row) * KPAD + k0 + kc * 8;
            int loff = (c >> 6) * 1024;  // wave-uniform LDS base
            gld_lds16(xhi + goA, (char*)&Ah[0][0] + loff);
            gld_lds16(xlo + goA, (char*)&Al[0][0] + loff);
            gld_lds16(ehi + goB, (char*)&Bh[0][0] + loff);
            gld_lds16(elo + goB, (char*)&Bl[0][0] + loff);
        }
        __syncthreads();

        f16x8 a_h[4], a_l[4];
        #pragma unroll
        for (int i = 0; i < 4; ++i) {
            a_h[i] = *(const f16x8*)&Ah[wr + i * 16 + lr][ko * 8];
            a_l[i] = *(const f16x8*)&Al[wr + i * 16 + lr][ko * 8];
        }
        #pragma unroll
        for (int j = 0; j < 4; ++j) {
            f16x8 b_h = *(const f16x8*)&Bh[wc + j * 16 + lr][ko * 8];
            f16x8 b_l = *(const f16x8*)&Bl[wc + j * 16 + lr][ko * 8];
            #pragma unroll
            for (int i = 0; i < 4; ++i) {
                acc[i][j] = __builtin_amdgcn_mfma_f32_16x16x32_f16(a_h[i], b_l, acc[i][j], 0, 0, 0);
                acc[i][j] = __builtin_amdgcn_mfma_f32_16x16x32_f16(a_l[i], b_h, acc[i][j], 0, 0, 0);
                acc[i][j] = __builtin_amdgcn_mfma_f32_16x16x32_f16(a_h[i], b_h, acc[i][j], 0, 0, 0);
            }
        }
        __syncthreads();
    }

    // epilogue: d = xx + ee - 2*dot ; enc = 1/d ; deterministic partial group sums
    const int g = blockIdx.y >> 1, half = blockIdx.y & 1;
    #pragma unroll
    for (int i = 0; i < 4; ++i) {
        #pragma unroll
        for (int r = 0; r < 4; ++r) {
            int row = m0 + wr + i * 16 + ko * 4 + r;
            float xm = xx[row];
            float rsum = 0.f;
            #pragma unroll
            for (int j = 0; j < 4; ++j) {
                int col = n0 + wc + j * 16 + lr;
                float dd = fmaf(-2.f, acc[i][j][r], xm + ee[col]);
                rsum += dd;
                enc[(size_t)row * N_CLS + col] = 1.0f / dd;
            }
            rsum += __shfl_xor(rsum, 1, 64);
            rsum += __shfl_xor(rsum, 2, 64);
            rsum += __shfl_xor(rsum, 4, 64);
            rsum += __shfl_xor(rsum, 8, 64);
            if (lr == 0)
                gsumP[(size_t)row * (NGRP * 4) + g * 4 + half * 2 + (wc >> 6)] = rsum;
        }
    }
}

// ---------------- fallback: fp32 VALU distance GEMM (R1 kernel) ----------------
__global__ __launch_bounds__(256) void k_dist(const float* __restrict__ x,
                                              const float* __restrict__ emb,
                                              const float* __restrict__ xx,
                                              const float* __restrict__ ee,
                                              float* __restrict__ enc,
                                              float* __restrict__ gsum) {
    __shared__ float As[16][36];
    __shared__ float Bs[16][260];
    const int tid = threadIdx.x;
    const int m0  = blockIdx.x * 32;
    const int g   = blockIdx.y;
    const int j0  = g * CPG;
    const int ty  = tid >> 5;
    const int tx  = tid & 31;
    float acc[4][8];
    #pragma unroll
    for (int i = 0; i < 4; ++i)
        #pragma unroll
        for (int j = 0; j < 8; ++j) acc[i][j] = 0.f;
    const int kk = tid & 15, rbase = tid >> 4;
    for (int k0 = 0; k0 < EDIM; k0 += 16) {
        #pragma unroll
        for (int p = 0; p < 2; ++p) {
            int r = p * 16 + rbase;
            As[kk][r] = x[(size_t)(m0 + r) * EDIM + k0 + kk];
        }
        #pragma unroll
        for (int p = 0; p < 16; ++p) {
            int c = p * 16 + rbase;
            Bs[kk][c] = emb[(size_t)(j0 + c) * EDIM + k0 + kk];
        }
        __syncthreads();
        #pragma unroll
        for (int k = 0; k < 16; ++k) {
            float4 a  = *(const float4*)&As[k][ty * 4];
            float4 b0 = *(const float4*)&Bs[k][tx * 4];
            float4 b1 = *(const float4*)&Bs[k][128 + tx * 4];
            float av[4] = {a.x, a.y, a.z, a.w};
            float bv[8] = {b0.x, b0.y, b0.z, b0.w, b1.x, b1.y, b1.z, b1.w};
            #pragma unroll
            for (int i = 0; i < 4; ++i)
                #pragma unroll
                for (int j = 0; j < 8; ++j)
                    acc[i][j] = fmaf(av[i], bv[j], acc[i][j]);
        }
        __syncthreads();
    }
    float rp[4];
    #pragma unroll
    for (int i = 0; i < 4; ++i) {
        int m = m0 + ty * 4 + i;
        float xm = xx[m];
        float rsum = 0.f;
        float* erow = enc + (size_t)m * N_CLS + j0;
        #pragma unroll
        for (int j = 0; j < 8; ++j) {
            int c = (j < 4) ? (tx * 4 + j) : (128 + tx * 4 + (j - 4));
            float t = xm + ee[j0 + c];
            float d = fmaf(-2.f, acc[i][j], t);
            rsum += d;
            erow[c] = 1.0f / d;
        }
        rp[i] = rsum;
    }
    #pragma unroll
    for (int i = 0; i < 4; ++i) {
        float s = rp[i];
        s += __shfl_xor(s, 1, 64);
        s += __shfl_xor(s, 2, 64);
        s += __shfl_xor(s, 4, 64);
        s += __shfl_xor(s, 8, 64);
        if (tx == 0) gsum[(size_t)(m0 + ty * 4 + i) * NGRP + g] = s;
    }
}

// ---------------- per-row selection, top-10, gather-sum: one wave per row ----------------
template <int NPART>
__global__ __launch_bounds__(256) void k_select(const float* __restrict__ x,
                                                const float* __restrict__ emb,
                                                const float* __restrict__ enc,
                                                const float* __restrict__ gsum,
                                                float* __restrict__ out0,
                                                float* __restrict__ rmse,
                                                unsigned int* __restrict__ hist) {
    const int wave = threadIdx.x >> 6;
    const int lane = threadIdx.x & 63;
    const int m = blockIdx.x * 4 + wave;

    const float* gs = gsum + (size_t)m * (NGRP * NPART);
    float bestv = 0.f; int bestg = 0;
    #pragma unroll
    for (int g = 0; g < NGRP; ++g) {
        float v = 0.f;
        #pragma unroll
        for (int p = 0; p < NPART; ++p) v += gs[g * NPART + p];
        if (g == 0 || v < bestv) { bestv = v; bestg = g; }
    }
    const int j0 = bestg * CPG;

    const float* pr = enc + (size_t)m * N_CLS + j0;
    float v[4];
    #pragma unroll
    for (int s = 0; s < 4; ++s) v[s] = pr[lane + 64 * s];

    float pv[NS]; int pidx[NS];
    #pragma unroll
    for (int t = 0; t < NS; ++t) {
        float bv = v[0]; int bs = 0;
        #pragma unroll
        for (int s = 1; s < 4; ++s) if (v[s] > bv) { bv = v[s]; bs = s; }
        int bidx = lane + 64 * bs;
        #pragma unroll
        for (int o = 1; o < 64; o <<= 1) {
            float ov = __shfl_xor(bv, o, 64);
            int   oi = __shfl_xor(bidx, o, 64);
            if (ov > bv || (ov == bv && oi < bidx)) { bv = ov; bidx = oi; }
        }
        pv[t] = bv; pidx[t] = bidx;
        if ((bidx & 63) == lane) v[bidx >> 6] = -INFINITY;
    }

    float psum = 0.f;
    #pragma unroll
    for (int t = 0; t < NS; ++t) psum += pv[t];
    float wnorm = fmaxf(psum, 1e-12f);
    float w[NS]; int gi[NS];
    #pragma unroll
    for (int t = 0; t < NS; ++t) { w[t] = pv[t] / wnorm; gi[t] = j0 + pidx[t]; }

    if (lane == 0) atomicAdd(&hist[gi[0]], 1u);

    const float* xr = x + (size_t)m * EDIM;
    float* orow = out0 + (size_t)m * EDIM;
    float sq = 0.f;
    for (int d = lane; d < EDIM; d += 64) {
        float o = 0.f;
        #pragma unroll
        for (int t = 0; t < NS; ++t) o = fmaf(w[t], emb[(size_t)gi[t] * EDIM + d], o);
        float xv = xr[d];
        float diff = xv - o;
        sq = fmaf(diff, diff, sq);
        orow[d] = (o - xv) + xv;
    }
    #pragma unroll
    for (int o = 32; o; o >>= 1) sq += __shfl_xor(sq, o, 64);
    if (lane == 0) rmse[m] = sq;
}

// ---------------- final deterministic reduction: loss + entropy ----------------
__global__ __launch_bounds__(1024) void k_final(const float* __restrict__ rmse,
                                                const unsigned int* __restrict__ hist,
                                                float* __restrict__ loss_out,
                                                float* __restrict__ ent_out) {
    __shared__ float red[1024];
    const int t = threadIdx.x;

    float s = 0.f;
    for (int i = t; i < M_ROWS; i += 1024) s += rmse[i];
    red[t] = s; __syncthreads();
    for (int off = 512; off; off >>= 1) {
        if (t < off) red[t] += red[t + off];
        __syncthreads();
    }
    if (t == 0) {
        float q = red[0] / 13107200.0f;
        loss_out[0] = q + 0.25f * q;
    }
    __syncthreads();

    float e = 0.f;
    for (int i = t; i < N_CLS; i += 1024) {
        unsigned int h = hist[i];
        if (h > 0) {
            float prb = (float)h / 32768.0f;
            e -= prb * logf(prb);
        }
    }
    red[t] = e; __syncthreads();
    for (int off = 512; off; off >>= 1) {
        if (t < off) red[t] += red[t + off];
        __syncthreads();
    }
    if (t == 0) ent_out[0] = red[0];
}

extern "C" void kernel_launch(void* const* d_in, const int* in_sizes, int n_in,
                              void* d_out, int out_size, void* d_ws, size_t ws_size,
                              hipStream_t stream) {
    const float* x   = (const float*)d_in[0];   // [32768, 400]
    const float* emb = (const float*)d_in[1];   // [2048, 400]

    float* out      = (float*)d_out;
    float* loss_out = out;
    float* out0     = out + 1;
    float* ent_out  = out + 1 + M_ROWS * EDIM;
    float* enc      = out + 2 + M_ROWS * EDIM;

    float* ws    = (float*)d_ws;
    float* ee    = ws;
    float* xx    = ee + N_CLS;
    float* gsumP = xx + M_ROWS;                       // [M][NGRP][4] (fast) or [M][NGRP] (fallback)
    float* rmse  = gsumP + (size_t)M_ROWS * NGRP * 4;
    unsigned int* hist = (unsigned int*)(rmse + M_ROWS);
    float* fend  = rmse + M_ROWS + N_CLS;

    unsigned short* xhi = (unsigned short*)fend;
    unsigned short* xlo = xhi + (size_t)M_ROWS * KPAD;
    unsigned short* ehi = xlo + (size_t)M_ROWS * KPAD;
    unsigned short* elo = ehi + (size_t)N_CLS * KPAD;
    size_t need = (size_t)((char*)(elo + (size_t)N_CLS * KPAD) - (char*)d_ws);

    hipMemsetAsync(hist, 0, N_CLS * sizeof(unsigned int), stream);

    if (ws_size >= need) {
        k_split<<<M_ROWS / 4, 256, 0, stream>>>(x, xhi, xlo, xx, M_ROWS);
        k_split<<<N_CLS / 4, 256, 0, stream>>>(emb, ehi, elo, ee, N_CLS);
        dim3 grid(M_ROWS / 128, N_CLS / 128);
        k_dist_mfma<<<grid, 256, 0, stream>>>(xhi, xlo, ehi, elo, xx, ee, enc, gsumP);
        k_select<4><<<M_ROWS / 4, 256, 0, stream>>>(x, emb, enc, gsumP, out0, rmse, hist);
    } else {
        k_sumsq<<<N_CLS / 4, 256, 0, stream>>>(emb, ee, N_CLS);
        k_sumsq<<<M_ROWS / 4, 256, 0, stream>>>(x, xx, M_ROWS);
        dim3 g2(M_ROWS / 32, NGRP);
        k_dist<<<g2, 256, 0, stream>>>(x, emb, xx, ee, enc, gsumP);
        k_select<1><<<M_ROWS / 4, 256, 0, stream>>>(x, emb, enc, gsumP, out0, rmse, hist);
    }

    k_final<<<1, 1024, 0, stream>>>(rmse, hist, loss_out, ent_out);
}